// Round 15
// baseline (449.108 us; speedup 1.0000x reference)
//
#include <hip/hip_runtime.h>
#include <hip/hip_bf16.h>

#define B_ 64
#define L_ 512
#define H_ 1024
#define A_ 1024

typedef short bf16x8 __attribute__((ext_vector_type(8)));
typedef float f32x4 __attribute__((ext_vector_type(4)));

__device__ __forceinline__ void gld16(const void* g, void* l) {
  __builtin_amdgcn_global_load_lds((const __attribute__((address_space(1))) void*)g,
                                   (__attribute__((address_space(3))) void*)l, 16, 0, 0);
}

__device__ __forceinline__ unsigned short f2bf(float f) {
  unsigned u = __builtin_bit_cast(unsigned, f);
  u = (u + 0x7fffu + ((u >> 16) & 1u)) >> 16;
  return (unsigned short)u;
}

__device__ __forceinline__ unsigned short cvtbf(float f) {
  __hip_bfloat16 b = __float2bfloat16(f);
  return __builtin_bit_cast(unsigned short, b);
}

__device__ __forceinline__ float fast_tanh(float x) {
  float e = __expf(2.f * x);
  float r = __builtin_amdgcn_rcpf(e + 1.f);
  return __builtin_fmaf(-2.f, r, 1.f);
}

// ---------- K-1: Xb = bf16(concat(Xlt, Xrt)), streaming ----------
__global__ __launch_bounds__(256) void cvt_kernel(const float* __restrict__ lt,
                                                  const float* __restrict__ rt,
                                                  unsigned short* __restrict__ xb) {
  const size_t NC = (size_t)B_ * L_ * H_ / 8;
  size_t stride = (size_t)gridDim.x * blockDim.x;
  for (size_t c = (size_t)blockIdx.x * blockDim.x + threadIdx.x; c < 2 * NC; c += stride) {
    const float* src = (c < NC) ? (lt + c * 8) : (rt + (c - NC) * 8);
    float4 v0 = ((const float4*)src)[0];
    float4 v1 = ((const float4*)src)[1];
    bf16x8 o;
    o[0] = (short)cvtbf(v0.x); o[1] = (short)cvtbf(v0.y);
    o[2] = (short)cvtbf(v0.z); o[3] = (short)cvtbf(v0.w);
    o[4] = (short)cvtbf(v1.x); o[5] = (short)cvtbf(v1.y);
    o[6] = (short)cvtbf(v1.z); o[7] = (short)cvtbf(v1.w);
    *(bf16x8*)(xb + c * 8) = o;
  }
}

// ---------- K0: Wt[a][h] = bf16(W[h][a]) ----------
__global__ __launch_bounds__(256) void wtrans_kernel(const float* __restrict__ W,
                                                     unsigned short* __restrict__ Wt) {
  __shared__ float tile[32][33];
  int tx = threadIdx.x & 31, ty = threadIdx.x >> 5;
  int a0 = (blockIdx.x & 31) << 5, h0 = (blockIdx.x >> 5) << 5;
#pragma unroll
  for (int i = 0; i < 4; ++i) {
    int h = ty + i * 8;
    tile[h][tx] = W[(size_t)(h0 + h) * A_ + a0 + tx];
  }
  __syncthreads();
#pragma unroll
  for (int i = 0; i < 4; ++i) {
    int a = ty + i * 8;
    Wt[(size_t)(a0 + a) * H_ + h0 + tx] = f2bf(tile[tx][a]);
  }
}

// ================= 8-phase conveyor (R11 schedule, literal-kt unroll) =======
#define STG_A(buf, h, kt) {                                                 \
    gld16(gA##h    + (kt) * 64, &As[buf][(h) * 8192 + lofs]);               \
    gld16(gA##h##b + (kt) * 64, &As[buf][(h) * 8192 + 4096 + lofs]); }
#define STG_B(buf, h, kt) {                                                 \
    gld16(gB##h    + (kt) * 64, &Bs[buf][(h) * 8192 + lofs]);               \
    gld16(gB##h##b + (kt) * 64, &Bs[buf][(h) * 8192 + 4096 + lofs]); }

#define LOAD_BQ(buf) { _Pragma("unroll") for (int ni = 0; ni < 4; ++ni) {   \
    int brow = wc * 64 + ni * 16 + l15;                                     \
    bq[ni][0] = *(const bf16x8*)&Bs[buf][brow * 64 + rd0];                  \
    bq[ni][1] = *(const bf16x8*)&Bs[buf][brow * 64 + rd1]; } }

// CKPT: 0 none, 1 vmcnt(4), 2 vmcnt(0)
#define PHASE(q, buf, STAGE_OP, CKPT) {                                     \
    bf16x8 aq0, aq1, aq2, aq3;                                              \
    { int ar = wr * 128 + (q) * 32 + l15;                                   \
      aq0 = *(const bf16x8*)&As[buf][ar * 64 + rd0];                        \
      aq1 = *(const bf16x8*)&As[buf][ar * 64 + rd1];                        \
      aq2 = *(const bf16x8*)&As[buf][(ar + 16) * 64 + rd0];                 \
      aq3 = *(const bf16x8*)&As[buf][(ar + 16) * 64 + rd1]; }               \
    STAGE_OP;                                                               \
    asm volatile("s_barrier" ::: "memory");                                 \
    __builtin_amdgcn_s_setprio(1);                                          \
    _Pragma("unroll") for (int ni = 0; ni < 4; ++ni) {                      \
      acc[(q)*2][ni] = __builtin_amdgcn_mfma_f32_16x16x32_bf16(             \
          aq0, bq[ni][0], acc[(q)*2][ni], 0, 0, 0);                         \
      acc[(q)*2][ni] = __builtin_amdgcn_mfma_f32_16x16x32_bf16(             \
          aq1, bq[ni][1], acc[(q)*2][ni], 0, 0, 0);                         \
      acc[(q)*2+1][ni] = __builtin_amdgcn_mfma_f32_16x16x32_bf16(           \
          aq2, bq[ni][0], acc[(q)*2+1][ni], 0, 0, 0);                       \
      acc[(q)*2+1][ni] = __builtin_amdgcn_mfma_f32_16x16x32_bf16(           \
          aq3, bq[ni][1], acc[(q)*2+1][ni], 0, 0, 0); }                     \
    __builtin_amdgcn_s_setprio(0);                                          \
    if ((CKPT) == 1) asm volatile("s_waitcnt vmcnt(4)" ::: "memory");       \
    if ((CKPT) == 2) asm volatile("s_waitcnt vmcnt(0)" ::: "memory");       \
    asm volatile("s_barrier" ::: "memory"); }

#define CONV_ITER(kt1, kt2, kt3) {                                          \
    LOAD_BQ(0);                                                             \
    PHASE(0, 0, STG_A(1, 0, kt1), 0);                                       \
    PHASE(1, 0, STG_A(1, 1, kt1), 0);                                       \
    PHASE(2, 0, STG_B(0, 0, kt2), 0);                                       \
    PHASE(3, 0, STG_B(0, 1, kt2), 1);                                       \
    LOAD_BQ(1);                                                             \
    PHASE(0, 1, STG_A(0, 0, kt2), 0);                                       \
    PHASE(1, 1, STG_A(0, 1, kt2), 0);                                       \
    PHASE(2, 1, STG_B(1, 0, kt3), 0);                                       \
    PHASE(3, 1, STG_B(1, 1, kt3), 1); }

// last iteration: computes kt14 (buf0) + kt15 (buf1); stages ONLY A15
// (needed by its own second half); ckpt after phase 3 = vmcnt(0) so buf1
// (A15 just staged + B15 staged last iter) is fully landed. Leaves zero
// outstanding loads -> next tile's prologue owns the LDS cleanly.
#define CONV_ITER_LAST() {                                                  \
    LOAD_BQ(0);                                                             \
    PHASE(0, 0, STG_A(1, 0, 15), 0);                                        \
    PHASE(1, 0, STG_A(1, 1, 15), 0);                                        \
    PHASE(2, 0, ;, 0);                                                      \
    PHASE(3, 0, ;, 2);                                                      \
    LOAD_BQ(1);                                                             \
    PHASE(0, 1, ;, 0);                                                      \
    PHASE(1, 1, ;, 0);                                                      \
    PHASE(2, 1, ;, 0);                                                      \
    PHASE(3, 1, ;, 0); }

#define CONV_BODY()                                                         \
  CONV_ITER(1, 2, 3)   CONV_ITER(3, 4, 5)   CONV_ITER(5, 6, 7)              \
  CONV_ITER(7, 8, 9)   CONV_ITER(9, 10, 11) CONV_ITER(11, 12, 13)           \
  CONV_ITER(13, 14, 15) CONV_ITER_LAST()

// prologue: kt0 full -> buf0 (8 loads), kt1 B -> buf1 (4 loads)
#define PROLOGUE()                                                          \
  STG_B(0, 0, 0); STG_B(0, 1, 0);                                           \
  STG_A(0, 0, 0); STG_A(0, 1, 0);                                           \
  STG_B(1, 0, 1); STG_B(1, 1, 1);

// ---------- K1: persistent 256x256 8-phase proj (256 blocks, 4 tiles each) --
// Pb = bf16(tanh(Xb @ Wt^T) [*diag]). Per block: fixed mt panel; loop nt=0..3.
// Tile j+1's prologue is issued BEFORE tile j's epilogue -> staging latency
// hides under tanh+stores; no re-dispatch; inner conveyor identical to R11.
__global__ __launch_bounds__(512, 2) void proj8_kernel(
    const unsigned short* __restrict__ Xb, const unsigned short* __restrict__ Wt,
    const float* __restrict__ diag, unsigned short* __restrict__ Pb) {
  __shared__ unsigned short As[2][256 * 64];
  __shared__ unsigned short Bs[2][256 * 64];
  int t = threadIdx.x;
  int lane = t & 63, wave = t >> 6;
  int wr = wave >> 2, wc = wave & 3;
  int l15 = lane & 15, l4 = lane >> 4;

  int mt = (int)blockIdx.x;            // 256 blocks, 1/CU
  int mrow0 = mt << 8;
  int isLt = (mt < 128);

  int rs = t >> 3, ss = t & 7;
  const unsigned short* gA0 = Xb + (size_t)(mrow0 + rs) * H_ + ((ss ^ (rs & 7)) << 3);
  const unsigned short* gA0b = gA0 + (size_t)64 * H_;
  const unsigned short* gA1  = gA0 + (size_t)128 * H_;
  const unsigned short* gA1b = gA0 + (size_t)192 * H_;
  // B pointers advance by one 256-col panel (256*H_ elements) per nt
  const unsigned short* gB0 = Wt + (size_t)rs * H_ + ((ss ^ (rs & 7)) << 3);
  const unsigned short* gB0b = gB0 + (size_t)64 * H_;
  const unsigned short* gB1  = gB0 + (size_t)128 * H_;
  const unsigned short* gB1b = gB0 + (size_t)192 * H_;
  int lofs = (rs * 8 + ss) * 8;

  int rd0 = (l4 ^ (l15 & 7)) * 8;
  int rd1 = ((4 + l4) ^ (l15 & 7)) * 8;

  f32x4 acc[8][4];
  bf16x8 bq[4][2];

  PROLOGUE();   // tile nt=0

#pragma unroll 1
  for (int nt = 0; nt < 4; ++nt) {
#pragma unroll
    for (int mi = 0; mi < 8; ++mi)
#pragma unroll
      for (int ni = 0; ni < 4; ++ni) acc[mi][ni] = f32x4{0.f, 0.f, 0.f, 0.f};

    asm volatile("s_waitcnt vmcnt(4)" ::: "memory");
    asm volatile("s_barrier" ::: "memory");

    CONV_BODY();

    // issue next tile's prologue BEFORE the epilogue (overlap with tanh/stores)
    if (nt < 3) {
      gB0 += (size_t)256 * H_; gB0b += (size_t)256 * H_;
      gB1 += (size_t)256 * H_; gB1b += (size_t)256 * H_;
      PROLOGUE();
    }

    // epilogue for this tile
    int ncol0 = nt << 8;
#pragma unroll
    for (int mi = 0; mi < 8; ++mi) {
#pragma unroll
      for (int ni = 0; ni < 4; ++ni) {
        int col = ncol0 + wc * 64 + ni * 16 + l15;
        float d = isLt ? diag[col] : 1.0f;
#pragma unroll
        for (int rr = 0; rr < 4; ++rr) {
          int row = mrow0 + wr * 128 + mi * 16 + l4 * 4 + rr;
          Pb[(size_t)row * A_ + col] = f2bf(fast_tanh(acc[mi][ni][rr]) * d);
        }
      }
    }
  }
}

// ---------- K2: 8-phase score: out[b][l][r] = (Plt.Prt^T) * ml * mr ----------
__global__ __launch_bounds__(512, 2) void score8_kernel(
    const unsigned short* __restrict__ Pb,
    const float* __restrict__ mask_lt, const float* __restrict__ mask_rt,
    float* __restrict__ out) {
  __shared__ unsigned short As[2][256 * 64];
  __shared__ unsigned short Bs[2][256 * 64];
  int t = threadIdx.x;
  int lane = t & 63, wave = t >> 6;
  int wr = wave >> 2, wc = wave & 3;
  int l15 = lane & 15, l4 = lane >> 4;

  int bid = (int)blockIdx.x;           // 256 blocks
  int x = bid & 7, k = bid >> 3;
  int pm = x + 8 * (k >> 1);           // [0,128)
  int b = pm >> 1, mt = pm & 1, nt = k & 1;

  int arow0 = b * 512 + mt * 256;
  int brow0 = 32768 + b * 512 + nt * 256;

  int rs = t >> 3, ss = t & 7;
  const unsigned short* gA0 = Pb + (size_t)(arow0 + rs) * H_ + ((ss ^ (rs & 7)) << 3);
  const unsigned short* gA0b = gA0 + (size_t)64 * H_;
  const unsigned short* gA1  = gA0 + (size_t)128 * H_;
  const unsigned short* gA1b = gA0 + (size_t)192 * H_;
  const unsigned short* gB0 = Pb + (size_t)(brow0 + rs) * H_ + ((ss ^ (rs & 7)) << 3);
  const unsigned short* gB0b = gB0 + (size_t)64 * H_;
  const unsigned short* gB1  = gB0 + (size_t)128 * H_;
  const unsigned short* gB1b = gB0 + (size_t)192 * H_;
  int lofs = (rs * 8 + ss) * 8;

  int rd0 = (l4 ^ (l15 & 7)) * 8;
  int rd1 = ((4 + l4) ^ (l15 & 7)) * 8;

  f32x4 acc[8][4] = {};
  bf16x8 bq[4][2];

  PROLOGUE();
  asm volatile("s_waitcnt vmcnt(4)" ::: "memory");
  asm volatile("s_barrier" ::: "memory");
  CONV_BODY();

  const float* mlp = mask_lt + b * L_;
  const float* mrp = mask_rt + b * L_;
  float* obase = out + (size_t)b * L_ * L_;
#pragma unroll
  for (int mi = 0; mi < 8; ++mi) {
#pragma unroll
    for (int ni = 0; ni < 4; ++ni) {
      int col = nt * 256 + wc * 64 + ni * 16 + l15;
      float mr = mrp[col];
#pragma unroll
      for (int rr = 0; rr < 4; ++rr) {
        int row = mt * 256 + wr * 128 + mi * 16 + l4 * 4 + rr;
        obase[(size_t)row * L_ + col] = acc[mi][ni][rr] * mlp[row] * mr;
      }
    }
  }
}

// ---------- K3: in-place row softmax over 512, then re-mask ----------
__global__ __launch_bounds__(256) void softmax_kernel(float* __restrict__ out,
                                                      const float* __restrict__ mask_lt,
                                                      const float* __restrict__ mask_rt) {
  int lane = threadIdx.x & 63, wave = threadIdx.x >> 6;
  int row = (int)blockIdx.x * 4 + wave;
  int b = row >> 9;
  float* p = out + (size_t)row * L_;
  float4 v0 = *(const float4*)(p + lane * 8);
  float4 v1 = *(const float4*)(p + lane * 8 + 4);
  float m = fmaxf(fmaxf(fmaxf(v0.x, v0.y), fmaxf(v0.z, v0.w)),
                  fmaxf(fmaxf(v1.x, v1.y), fmaxf(v1.z, v1.w)));
#pragma unroll
  for (int off = 32; off; off >>= 1) m = fmaxf(m, __shfl_xor(m, off));
  float e0 = __expf(v0.x - m), e1 = __expf(v0.y - m), e2 = __expf(v0.z - m), e3 = __expf(v0.w - m);
  float e4 = __expf(v1.x - m), e5 = __expf(v1.y - m), e6 = __expf(v1.z - m), e7 = __expf(v1.w - m);
  float s = ((e0 + e1) + (e2 + e3)) + ((e4 + e5) + (e6 + e7));
#pragma unroll
  for (int off = 32; off; off >>= 1) s += __shfl_xor(s, off);
  float sc = (1.0f / s) * mask_lt[row];
  const float* mrp = mask_rt + (b << 9) + lane * 8;
  float4 mr0 = *(const float4*)mrp;
  float4 mr1 = *(const float4*)(mrp + 4);
  float4 o0 = make_float4(e0 * sc * mr0.x, e1 * sc * mr0.y, e2 * sc * mr0.z, e3 * sc * mr0.w);
  float4 o1 = make_float4(e4 * sc * mr1.x, e5 * sc * mr1.y, e6 * sc * mr1.z, e7 * sc * mr1.w);
  *(float4*)(p + lane * 8) = o0;
  *(float4*)(p + lane * 8 + 4) = o1;
}

extern "C" void kernel_launch(void* const* d_in, const int* in_sizes, int n_in,
                              void* d_out, int out_size, void* d_ws, size_t ws_size,
                              hipStream_t stream) {
  const float* reps_lt = (const float*)d_in[0];
  const float* reps_rt = (const float*)d_in[1];
  const float* mask_lt = (const float*)d_in[2];
  const float* mask_rt = (const float*)d_in[3];
  const float* attn_w1 = (const float*)d_in[4];
  const float* diag    = (const float*)d_in[5];
  float* out = (float*)d_out;

  unsigned short* wt = (unsigned short*)d_ws;           // 2 MB
  unsigned short* pb = wt + (size_t)H_ * A_;            // 128 MB
  unsigned short* xb = pb + (size_t)B_ * L_ * A_ * 2;   // 128 MB

  hipLaunchKernelGGL(wtrans_kernel, dim3(1024), dim3(256), 0, stream, attn_w1, wt);
  hipLaunchKernelGGL(cvt_kernel, dim3(8192), dim3(256), 0, stream,
                     reps_lt, reps_rt, xb);
  hipLaunchKernelGGL(proj8_kernel, dim3(256), dim3(512), 0, stream,
                     xb, wt, diag, pb);
  hipLaunchKernelGGL(score8_kernel, dim3(256), dim3(512), 0, stream,
                     pb, mask_lt, mask_rt, out);
  hipLaunchKernelGGL(softmax_kernel, dim3(8192), dim3(256), 0, stream,
                     out, mask_lt, mask_rt);
}

// Round 16
// 300.898 us; speedup vs baseline: 1.4926x; 1.4926x over previous
//
#include <hip/hip_runtime.h>
#include <hip/hip_bf16.h>

#define B_ 64
#define L_ 512
#define H_ 1024
#define A_ 1024

typedef short bf16x8 __attribute__((ext_vector_type(8)));
typedef float f32x4 __attribute__((ext_vector_type(4)));
typedef float f32x16 __attribute__((ext_vector_type(16)));

__device__ __forceinline__ void gld16(const void* g, void* l) {
  __builtin_amdgcn_global_load_lds((const __attribute__((address_space(1))) void*)g,
                                   (__attribute__((address_space(3))) void*)l, 16, 0, 0);
}

__device__ __forceinline__ unsigned short f2bf(float f) {
  unsigned u = __builtin_bit_cast(unsigned, f);
  u = (u + 0x7fffu + ((u >> 16) & 1u)) >> 16;
  return (unsigned short)u;
}

__device__ __forceinline__ unsigned short cvtbf(float f) {
  __hip_bfloat16 b = __float2bfloat16(f);
  return __builtin_bit_cast(unsigned short, b);
}

__device__ __forceinline__ float fast_tanh(float x) {
  float e = __expf(2.f * x);
  float r = __builtin_amdgcn_rcpf(e + 1.f);
  return __builtin_fmaf(-2.f, r, 1.f);
}

// ---------- K-1: Xb = bf16(concat(Xlt, Xrt)), streaming ----------
__global__ __launch_bounds__(256) void cvt_kernel(const float* __restrict__ lt,
                                                  const float* __restrict__ rt,
                                                  unsigned short* __restrict__ xb) {
  const size_t NC = (size_t)B_ * L_ * H_ / 8;
  size_t stride = (size_t)gridDim.x * blockDim.x;
  for (size_t c = (size_t)blockIdx.x * blockDim.x + threadIdx.x; c < 2 * NC; c += stride) {
    const float* src = (c < NC) ? (lt + c * 8) : (rt + (c - NC) * 8);
    float4 v0 = ((const float4*)src)[0];
    float4 v1 = ((const float4*)src)[1];
    bf16x8 o;
    o[0] = (short)cvtbf(v0.x); o[1] = (short)cvtbf(v0.y);
    o[2] = (short)cvtbf(v0.z); o[3] = (short)cvtbf(v0.w);
    o[4] = (short)cvtbf(v1.x); o[5] = (short)cvtbf(v1.y);
    o[6] = (short)cvtbf(v1.z); o[7] = (short)cvtbf(v1.w);
    *(bf16x8*)(xb + c * 8) = o;
  }
}

// ---------- K0: Wt[a][h] = bf16(W[h][a]) ----------
__global__ __launch_bounds__(256) void wtrans_kernel(const float* __restrict__ W,
                                                     unsigned short* __restrict__ Wt) {
  __shared__ float tile[32][33];
  int tx = threadIdx.x & 31, ty = threadIdx.x >> 5;
  int a0 = (blockIdx.x & 31) << 5, h0 = (blockIdx.x >> 5) << 5;
#pragma unroll
  for (int i = 0; i < 4; ++i) {
    int h = ty + i * 8;
    tile[h][tx] = W[(size_t)(h0 + h) * A_ + a0 + tx];
  }
  __syncthreads();
#pragma unroll
  for (int i = 0; i < 4; ++i) {
    int a = ty + i * 8;
    Wt[(size_t)(a0 + a) * H_ + h0 + tx] = f2bf(tile[tx][a]);
  }
}

// ============ 8-phase conveyor (R14 schedule) with 32x32x16 MFMA ============
// Staging / barriers / vmcnt byte-identical to R14 (proven). Only the phase
// compute changed: per phase one 32-row block x 2 32-col blocks x K=64
// = 8 v_mfma_f32_32x32x16_bf16 (was 16 16x16x32). Frag reads: one
// ds_read_b128 per (row-block, k-slice); row = lane&31, k-chunk = 2j+(lane>>5),
// slot = chunk ^ (lane&7) (same XOR family -> full per-8-lane bank coverage).
#define STG_A(buf, h, kt) {                                                 \
    gld16(gA##h    + (kt) * 64, &As[buf][(h) * 8192 + lofs]);               \
    gld16(gA##h##b + (kt) * 64, &As[buf][(h) * 8192 + 4096 + lofs]); }
#define STG_B(buf, h, kt) {                                                 \
    gld16(gB##h    + (kt) * 64, &Bs[buf][(h) * 8192 + lofs]);               \
    gld16(gB##h##b + (kt) * 64, &Bs[buf][(h) * 8192 + 4096 + lofs]); }

#define LOAD_BQ(buf) { _Pragma("unroll") for (int cb = 0; cb < 2; ++cb) {   \
    int br = wc * 64 + cb * 32 + l31;                                       \
    _Pragma("unroll") for (int j = 0; j < 4; ++j)                           \
      bq[cb][j] = *(const bf16x8*)&Bs[buf][br * 64 + rdA[j]]; } }

// CKPT: 0 none, 1 vmcnt(4)
#define PHASE(rb, buf, STAGE_OP, CKPT) {                                    \
    bf16x8 aq0, aq1, aq2, aq3;                                              \
    { int ar = wr * 128 + (rb) * 32 + l31;                                  \
      aq0 = *(const bf16x8*)&As[buf][ar * 64 + rdA[0]];                     \
      aq1 = *(const bf16x8*)&As[buf][ar * 64 + rdA[1]];                     \
      aq2 = *(const bf16x8*)&As[buf][ar * 64 + rdA[2]];                     \
      aq3 = *(const bf16x8*)&As[buf][ar * 64 + rdA[3]]; }                   \
    STAGE_OP;                                                               \
    asm volatile("s_barrier" ::: "memory");                                 \
    __builtin_amdgcn_s_setprio(1);                                          \
    _Pragma("unroll") for (int cb = 0; cb < 2; ++cb) {                      \
      acc[rb][cb] = __builtin_amdgcn_mfma_f32_32x32x16_bf16(                \
          aq0, bq[cb][0], acc[rb][cb], 0, 0, 0);                            \
      acc[rb][cb] = __builtin_amdgcn_mfma_f32_32x32x16_bf16(                \
          aq1, bq[cb][1], acc[rb][cb], 0, 0, 0);                            \
      acc[rb][cb] = __builtin_amdgcn_mfma_f32_32x32x16_bf16(                \
          aq2, bq[cb][2], acc[rb][cb], 0, 0, 0);                            \
      acc[rb][cb] = __builtin_amdgcn_mfma_f32_32x32x16_bf16(                \
          aq3, bq[cb][3], acc[rb][cb], 0, 0, 0); }                          \
    __builtin_amdgcn_s_setprio(0);                                          \
    if (CKPT) asm volatile("s_waitcnt vmcnt(4)" ::: "memory");              \
    asm volatile("s_barrier" ::: "memory"); }

#define CONV_ITER(kt1, kt2, kt3) {                                          \
    LOAD_BQ(0);                                                             \
    PHASE(0, 0, STG_A(1, 0, kt1), 0);                                       \
    PHASE(1, 0, STG_A(1, 1, kt1), 0);                                       \
    PHASE(2, 0, STG_B(0, 0, kt2), 0);                                       \
    PHASE(3, 0, STG_B(0, 1, kt2), 1);                                       \
    LOAD_BQ(1);                                                             \
    PHASE(0, 1, STG_A(0, 0, kt2), 0);                                       \
    PHASE(1, 1, STG_A(0, 1, kt2), 0);                                       \
    PHASE(2, 1, STG_B(1, 0, kt3), 0);                                       \
    PHASE(3, 1, STG_B(1, 1, kt3), 1); }

#define CONVEYOR_LIT()                                                      \
  STG_B(0, 0, 0); STG_B(0, 1, 0);                                           \
  STG_A(0, 0, 0); STG_A(0, 1, 0);                                           \
  STG_B(1, 0, 1); STG_B(1, 1, 1);                                           \
  asm volatile("s_waitcnt vmcnt(4)" ::: "memory");                          \
  asm volatile("s_barrier" ::: "memory");                                   \
  CONV_ITER(1, 2, 3)   CONV_ITER(3, 4, 5)   CONV_ITER(5, 6, 7)              \
  CONV_ITER(7, 8, 9)   CONV_ITER(9, 10, 11) CONV_ITER(11, 12, 13)           \
  CONV_ITER(13, 14, 15) CONV_ITER(15, 0, 1)

// ---------- K1: 256x256 8-phase proj: Pb = bf16(tanh(Xb@Wt^T)[*diag]) ------
__global__ __launch_bounds__(512, 2) void proj8_kernel(
    const unsigned short* __restrict__ Xb, const unsigned short* __restrict__ Wt,
    const float* __restrict__ diag, unsigned short* __restrict__ Pb) {
  __shared__ unsigned short As[2][256 * 64];
  __shared__ unsigned short Bs[2][256 * 64];
  int t = threadIdx.x;
  int lane = t & 63, wave = t >> 6;
  int wr = wave >> 2, wc = wave & 3;   // 2M x 4N; per-wave 128x64 out
  int l31 = lane & 31, h5 = lane >> 5;

  int bid = (int)blockIdx.x;           // 1024 blocks, XCD swizzle (R14)
  int x = bid & 7, k = bid >> 3;
  int mt = x + 8 * (k >> 2);           // [0,256)
  int nt = k & 3;
  int mrow0 = mt << 8, ncol0 = nt << 8;
  int isLt = (mt < 128);

  int rs = t >> 3, ss = t & 7;
  const unsigned short* gA0 = Xb + (size_t)(mrow0 + rs) * H_ + ((ss ^ (rs & 7)) << 3);
  const unsigned short* gA0b = gA0 + (size_t)64 * H_;
  const unsigned short* gA1  = gA0 + (size_t)128 * H_;
  const unsigned short* gA1b = gA0 + (size_t)192 * H_;
  const unsigned short* gB0 = Wt + (size_t)(ncol0 + rs) * H_ + ((ss ^ (rs & 7)) << 3);
  const unsigned short* gB0b = gB0 + (size_t)64 * H_;
  const unsigned short* gB1  = gB0 + (size_t)128 * H_;
  const unsigned short* gB1b = gB0 + (size_t)192 * H_;
  int lofs = (rs * 8 + ss) * 8;

  int rdA[4];
#pragma unroll
  for (int j = 0; j < 4; ++j) rdA[j] = ((2 * j + h5) ^ (lane & 7)) * 8;

  f32x16 acc[4][2] = {};
  bf16x8 bq[2][4];

  CONVEYOR_LIT();

#pragma unroll
  for (int rb = 0; rb < 4; ++rb) {
#pragma unroll
    for (int cb = 0; cb < 2; ++cb) {
      int col = ncol0 + wc * 64 + cb * 32 + l31;
      float d = isLt ? diag[col] : 1.0f;
#pragma unroll
      for (int reg = 0; reg < 16; ++reg) {
        int row = mrow0 + wr * 128 + rb * 32 + (reg & 3) + 8 * (reg >> 2) + 4 * h5;
        Pb[(size_t)row * A_ + col] = f2bf(fast_tanh(acc[rb][cb][reg]) * d);
      }
    }
  }
}

// ---------- K2: 8-phase score: out[b][l][r] = (Plt.Prt^T) * ml * mr ----------
__global__ __launch_bounds__(512, 2) void score8_kernel(
    const unsigned short* __restrict__ Pb,
    const float* __restrict__ mask_lt, const float* __restrict__ mask_rt,
    float* __restrict__ out) {
  __shared__ unsigned short As[2][256 * 64];
  __shared__ unsigned short Bs[2][256 * 64];
  int t = threadIdx.x;
  int lane = t & 63, wave = t >> 6;
  int wr = wave >> 2, wc = wave & 3;
  int l31 = lane & 31, h5 = lane >> 5;

  int bid = (int)blockIdx.x;           // 256 blocks
  int x = bid & 7, k = bid >> 3;
  int pm = x + 8 * (k >> 1);           // [0,128)
  int b = pm >> 1, mt = pm & 1, nt = k & 1;

  int arow0 = b * 512 + mt * 256;
  int brow0 = 32768 + b * 512 + nt * 256;

  int rs = t >> 3, ss = t & 7;
  const unsigned short* gA0 = Pb + (size_t)(arow0 + rs) * H_ + ((ss ^ (rs & 7)) << 3);
  const unsigned short* gA0b = gA0 + (size_t)64 * H_;
  const unsigned short* gA1  = gA0 + (size_t)128 * H_;
  const unsigned short* gA1b = gA0 + (size_t)192 * H_;
  const unsigned short* gB0 = Pb + (size_t)(brow0 + rs) * H_ + ((ss ^ (rs & 7)) << 3);
  const unsigned short* gB0b = gB0 + (size_t)64 * H_;
  const unsigned short* gB1  = gB0 + (size_t)128 * H_;
  const unsigned short* gB1b = gB0 + (size_t)192 * H_;
  int lofs = (rs * 8 + ss) * 8;

  int rdA[4];
#pragma unroll
  for (int j = 0; j < 4; ++j) rdA[j] = ((2 * j + h5) ^ (lane & 7)) * 8;

  f32x16 acc[4][2] = {};
  bf16x8 bq[2][4];

  CONVEYOR_LIT();

  const float* mlp = mask_lt + b * L_;
  const float* mrp = mask_rt + b * L_;
  float* obase = out + (size_t)b * L_ * L_;
#pragma unroll
  for (int rb = 0; rb < 4; ++rb) {
#pragma unroll
    for (int cb = 0; cb < 2; ++cb) {
      int col = nt * 256 + wc * 64 + cb * 32 + l31;
      float mr = mrp[col];
#pragma unroll
      for (int reg = 0; reg < 16; ++reg) {
        int row = mt * 256 + wr * 128 + rb * 32 + (reg & 3) + 8 * (reg >> 2) + 4 * h5;
        obase[(size_t)row * L_ + col] = acc[rb][cb][reg] * mlp[row] * mr;
      }
    }
  }
}

// ---------- K3: in-place row softmax over 512, then re-mask ----------
__global__ __launch_bounds__(256) void softmax_kernel(float* __restrict__ out,
                                                      const float* __restrict__ mask_lt,
                                                      const float* __restrict__ mask_rt) {
  int lane = threadIdx.x & 63, wave = threadIdx.x >> 6;
  int row = (int)blockIdx.x * 4 + wave;
  int b = row >> 9;
  float* p = out + (size_t)row * L_;
  float4 v0 = *(const float4*)(p + lane * 8);
  float4 v1 = *(const float4*)(p + lane * 8 + 4);
  float m = fmaxf(fmaxf(fmaxf(v0.x, v0.y), fmaxf(v0.z, v0.w)),
                  fmaxf(fmaxf(v1.x, v1.y), fmaxf(v1.z, v1.w)));
#pragma unroll
  for (int off = 32; off; off >>= 1) m = fmaxf(m, __shfl_xor(m, off));
  float e0 = __expf(v0.x - m), e1 = __expf(v0.y - m), e2 = __expf(v0.z - m), e3 = __expf(v0.w - m);
  float e4 = __expf(v1.x - m), e5 = __expf(v1.y - m), e6 = __expf(v1.z - m), e7 = __expf(v1.w - m);
  float s = ((e0 + e1) + (e2 + e3)) + ((e4 + e5) + (e6 + e7));
#pragma unroll
  for (int off = 32; off; off >>= 1) s += __shfl_xor(s, off);
  float sc = (1.0f / s) * mask_lt[row];
  const float* mrp = mask_rt + (b << 9) + lane * 8;
  float4 mr0 = *(const float4*)mrp;
  float4 mr1 = *(const float4*)(mrp + 4);
  float4 o0 = make_float4(e0 * sc * mr0.x, e1 * sc * mr0.y, e2 * sc * mr0.z, e3 * sc * mr0.w);
  float4 o1 = make_float4(e4 * sc * mr1.x, e5 * sc * mr1.y, e6 * sc * mr1.z, e7 * sc * mr1.w);
  *(float4*)(p + lane * 8) = o0;
  *(float4*)(p + lane * 8 + 4) = o1;
}

extern "C" void kernel_launch(void* const* d_in, const int* in_sizes, int n_in,
                              void* d_out, int out_size, void* d_ws, size_t ws_size,
                              hipStream_t stream) {
  const float* reps_lt = (const float*)d_in[0];
  const float* reps_rt = (const float*)d_in[1];
  const float* mask_lt = (const float*)d_in[2];
  const float* mask_rt = (const float*)d_in[3];
  const float* attn_w1 = (const float*)d_in[4];
  const float* diag    = (const float*)d_in[5];
  float* out = (float*)d_out;

  unsigned short* wt = (unsigned short*)d_ws;           // 2 MB
  unsigned short* pb = wt + (size_t)H_ * A_;            // 128 MB
  unsigned short* xb = pb + (size_t)B_ * L_ * A_ * 2;   // 128 MB

  hipLaunchKernelGGL(wtrans_kernel, dim3(1024), dim3(256), 0, stream, attn_w1, wt);
  hipLaunchKernelGGL(cvt_kernel, dim3(8192), dim3(256), 0, stream,
                     reps_lt, reps_rt, xb);
  hipLaunchKernelGGL(proj8_kernel, dim3(1024), dim3(512), 0, stream,
                     xb, wt, diag, pb);
  hipLaunchKernelGGL(score8_kernel, dim3(256), dim3(512), 0, stream,
                     pb, mask_lt, mask_rt, out);
  hipLaunchKernelGGL(softmax_kernel, dim3(8192), dim3(256), 0, stream,
                     out, mask_lt, mask_rt);
}

// Round 17
// 281.428 us; speedup vs baseline: 1.5958x; 1.0692x over previous
//
#include <hip/hip_runtime.h>
#include <hip/hip_bf16.h>

#define B_ 64
#define L_ 512
#define H_ 1024
#define A_ 1024

typedef short bf16x8 __attribute__((ext_vector_type(8)));
typedef float f32x4 __attribute__((ext_vector_type(4)));

__device__ __forceinline__ void gld16(const void* g, void* l) {
  __builtin_amdgcn_global_load_lds((const __attribute__((address_space(1))) void*)g,
                                   (__attribute__((address_space(3))) void*)l, 16, 0, 0);
}

__device__ __forceinline__ unsigned short f2bf(float f) {
  unsigned u = __builtin_bit_cast(unsigned, f);
  u = (u + 0x7fffu + ((u >> 16) & 1u)) >> 16;
  return (unsigned short)u;
}

__device__ __forceinline__ unsigned short cvtbf(float f) {
  __hip_bfloat16 b = __float2bfloat16(f);
  return __builtin_bit_cast(unsigned short, b);
}

__device__ __forceinline__ float fast_tanh(float x) {
  float e = __expf(2.f * x);
  float r = __builtin_amdgcn_rcpf(e + 1.f);
  return __builtin_fmaf(-2.f, r, 1.f);
}

// ---------- K-1: Xb = bf16(concat(Xlt, Xrt)), streaming ----------
__global__ __launch_bounds__(256) void cvt_kernel(const float* __restrict__ lt,
                                                  const float* __restrict__ rt,
                                                  unsigned short* __restrict__ xb) {
  const size_t NC = (size_t)B_ * L_ * H_ / 8;
  size_t stride = (size_t)gridDim.x * blockDim.x;
  for (size_t c = (size_t)blockIdx.x * blockDim.x + threadIdx.x; c < 2 * NC; c += stride) {
    const float* src = (c < NC) ? (lt + c * 8) : (rt + (c - NC) * 8);
    float4 v0 = ((const float4*)src)[0];
    float4 v1 = ((const float4*)src)[1];
    bf16x8 o;
    o[0] = (short)cvtbf(v0.x); o[1] = (short)cvtbf(v0.y);
    o[2] = (short)cvtbf(v0.z); o[3] = (short)cvtbf(v0.w);
    o[4] = (short)cvtbf(v1.x); o[5] = (short)cvtbf(v1.y);
    o[6] = (short)cvtbf(v1.z); o[7] = (short)cvtbf(v1.w);
    *(bf16x8*)(xb + c * 8) = o;
  }
}

// ---------- K0: Wt[a][h] = bf16(W[h][a]) ----------
__global__ __launch_bounds__(256) void wtrans_kernel(const float* __restrict__ W,
                                                     unsigned short* __restrict__ Wt) {
  __shared__ float tile[32][33];
  int tx = threadIdx.x & 31, ty = threadIdx.x >> 5;
  int a0 = (blockIdx.x & 31) << 5, h0 = (blockIdx.x >> 5) << 5;
#pragma unroll
  for (int i = 0; i < 4; ++i) {
    int h = ty + i * 8;
    tile[h][tx] = W[(size_t)(h0 + h) * A_ + a0 + tx];
  }
  __syncthreads();
#pragma unroll
  for (int i = 0; i < 4; ++i) {
    int a = ty + i * 8;
    Wt[(size_t)(a0 + a) * H_ + h0 + tx] = f2bf(tile[tx][a]);
  }
}

// ================= 8-phase conveyor (R14, proven 16x16 version) =============
#define STG_A(buf, h, kt) {                                                 \
    gld16(gA##h    + (kt) * 64, &As[buf][(h) * 8192 + lofs]);               \
    gld16(gA##h##b + (kt) * 64, &As[buf][(h) * 8192 + 4096 + lofs]); }
#define STG_B(buf, h, kt) {                                                 \
    gld16(gB##h    + (kt) * 64, &Bs[buf][(h) * 8192 + lofs]);               \
    gld16(gB##h##b + (kt) * 64, &Bs[buf][(h) * 8192 + 4096 + lofs]); }

#define LOAD_BQ(buf) { _Pragma("unroll") for (int ni = 0; ni < 4; ++ni) {   \
    int brow = wc * 64 + ni * 16 + l15;                                     \
    bq[ni][0] = *(const bf16x8*)&Bs[buf][brow * 64 + rd0];                  \
    bq[ni][1] = *(const bf16x8*)&Bs[buf][brow * 64 + rd1]; } }

#define PHASE(q, buf, STAGE_OP, CKPT) {                                     \
    bf16x8 aq0, aq1, aq2, aq3;                                              \
    { int ar = wr * 128 + (q) * 32 + l15;                                   \
      aq0 = *(const bf16x8*)&As[buf][ar * 64 + rd0];                        \
      aq1 = *(const bf16x8*)&As[buf][ar * 64 + rd1];                        \
      aq2 = *(const bf16x8*)&As[buf][(ar + 16) * 64 + rd0];                 \
      aq3 = *(const bf16x8*)&As[buf][(ar + 16) * 64 + rd1]; }               \
    STAGE_OP;                                                               \
    asm volatile("s_barrier" ::: "memory");                                 \
    __builtin_amdgcn_s_setprio(1);                                          \
    _Pragma("unroll") for (int ni = 0; ni < 4; ++ni) {                      \
      acc[(q)*2][ni] = __builtin_amdgcn_mfma_f32_16x16x32_bf16(             \
          aq0, bq[ni][0], acc[(q)*2][ni], 0, 0, 0);                         \
      acc[(q)*2][ni] = __builtin_amdgcn_mfma_f32_16x16x32_bf16(             \
          aq1, bq[ni][1], acc[(q)*2][ni], 0, 0, 0);                         \
      acc[(q)*2+1][ni] = __builtin_amdgcn_mfma_f32_16x16x32_bf16(           \
          aq2, bq[ni][0], acc[(q)*2+1][ni], 0, 0, 0);                       \
      acc[(q)*2+1][ni] = __builtin_amdgcn_mfma_f32_16x16x32_bf16(           \
          aq3, bq[ni][1], acc[(q)*2+1][ni], 0, 0, 0); }                     \
    __builtin_amdgcn_s_setprio(0);                                          \
    if (CKPT) asm volatile("s_waitcnt vmcnt(4)" ::: "memory");              \
    asm volatile("s_barrier" ::: "memory"); }

#define CONV_ITER(kt1, kt2, kt3) {                                          \
    LOAD_BQ(0);                                                             \
    PHASE(0, 0, STG_A(1, 0, kt1), 0);                                       \
    PHASE(1, 0, STG_A(1, 1, kt1), 0);                                       \
    PHASE(2, 0, STG_B(0, 0, kt2), 0);                                       \
    PHASE(3, 0, STG_B(0, 1, kt2), 1);                                       \
    LOAD_BQ(1);                                                             \
    PHASE(0, 1, STG_A(0, 0, kt2), 0);                                       \
    PHASE(1, 1, STG_A(0, 1, kt2), 0);                                       \
    PHASE(2, 1, STG_B(1, 0, kt3), 0);                                       \
    PHASE(3, 1, STG_B(1, 1, kt3), 1); }

#define CONVEYOR_LIT()                                                      \
  STG_B(0, 0, 0); STG_B(0, 1, 0);                                           \
  STG_A(0, 0, 0); STG_A(0, 1, 0);                                           \
  STG_B(1, 0, 1); STG_B(1, 1, 1);                                           \
  asm volatile("s_waitcnt vmcnt(4)" ::: "memory");                          \
  asm volatile("s_barrier" ::: "memory");                                   \
  CONV_ITER(1, 2, 3)   CONV_ITER(3, 4, 5)   CONV_ITER(5, 6, 7)              \
  CONV_ITER(7, 8, 9)   CONV_ITER(9, 10, 11) CONV_ITER(11, 12, 13)           \
  CONV_ITER(13, 14, 15) CONV_ITER(15, 0, 1)

// ---------- K1: 256x256 8-phase proj: Pb = bf16(tanh(Xb@Wt^T)[*diag]) ------
__global__ __launch_bounds__(512, 2) void proj8_kernel(
    const unsigned short* __restrict__ Xb, const unsigned short* __restrict__ Wt,
    const float* __restrict__ diag, unsigned short* __restrict__ Pb) {
  __shared__ unsigned short As[2][256 * 64];
  __shared__ unsigned short Bs[2][256 * 64];
  int t = threadIdx.x;
  int lane = t & 63, wave = t >> 6;
  int wr = wave >> 2, wc = wave & 3;
  int l15 = lane & 15, l4 = lane >> 4;

  int bid = (int)blockIdx.x;           // 1024 blocks, XCD swizzle
  int x = bid & 7, k = bid >> 3;
  int mt = x + 8 * (k >> 2);           // [0,256)
  int nt = k & 3;
  int mrow0 = mt << 8, ncol0 = nt << 8;
  int isLt = (mt < 128);

  int rs = t >> 3, ss = t & 7;
  const unsigned short* gA0 = Xb + (size_t)(mrow0 + rs) * H_ + ((ss ^ (rs & 7)) << 3);
  const unsigned short* gA0b = gA0 + (size_t)64 * H_;
  const unsigned short* gA1  = gA0 + (size_t)128 * H_;
  const unsigned short* gA1b = gA0 + (size_t)192 * H_;
  const unsigned short* gB0 = Wt + (size_t)(ncol0 + rs) * H_ + ((ss ^ (rs & 7)) << 3);
  const unsigned short* gB0b = gB0 + (size_t)64 * H_;
  const unsigned short* gB1  = gB0 + (size_t)128 * H_;
  const unsigned short* gB1b = gB0 + (size_t)192 * H_;
  int lofs = (rs * 8 + ss) * 8;

  int rd0 = (l4 ^ (l15 & 7)) * 8;
  int rd1 = ((4 + l4) ^ (l15 & 7)) * 8;

  f32x4 acc[8][4] = {};
  bf16x8 bq[4][2];

  CONVEYOR_LIT();

#pragma unroll
  for (int mi = 0; mi < 8; ++mi) {
#pragma unroll
    for (int ni = 0; ni < 4; ++ni) {
      int col = ncol0 + wc * 64 + ni * 16 + l15;
      float d = isLt ? diag[col] : 1.0f;
#pragma unroll
      for (int rr = 0; rr < 4; ++rr) {
        int row = mrow0 + wr * 128 + mi * 16 + l4 * 4 + rr;
        Pb[(size_t)row * A_ + col] = f2bf(fast_tanh(acc[mi][ni][rr]) * d);
      }
    }
  }
}

// ---------- K2: fused score+softmax ----------
// Tile M=128 (Plt rows) x N=512 (ALL Prt rows -> full softmax row in-block).
// 512 thr = 8 waves (2M x 4N); per wave 64x128, acc[4][8] f32x4.
// BK=32, THREE-buffer LDS ring (A 3x8KB + B 3x32KB = 120KB), prefetch
// distance 2 tiles, ckpt vmcnt(5) at tile end (tile j+1's 5 loads confirmed;
// j+2's 5 in flight). Stage(j+2) targets buf (j+2)%3 = (j-1)%3, whose readers
// drained 2 barriers ago. Epilogue: mask -> row-max (shfl_xor l15-group +
// LDS cross-wave) -> exp -> row-sum -> scale*masks -> f32 store.
__global__ __launch_bounds__(512) void ssmax_kernel(
    const unsigned short* __restrict__ Pb,
    const float* __restrict__ mask_lt, const float* __restrict__ mask_rt,
    float* __restrict__ out) {
  __shared__ unsigned short As2[3][128 * 32];  // 3 x 8 KB
  __shared__ unsigned short Bs2[3][512 * 32];  // 3 x 32 KB
  int t = threadIdx.x;
  int lane = t & 63, wave = t >> 6;
  int wr = wave >> 2, wc = wave & 3;   // 2M x 4N; wave = 64 rows x 128 cols
  int l15 = lane & 15, l4 = lane >> 4;

  // XCD swizzle: XCD x gets contiguous g = x*32 + k
  int bid = (int)blockIdx.x;           // 256 blocks
  int g = (bid & 7) * 32 + (bid >> 3);
  int b = g >> 2, mt = g & 3;

  int arow0 = b * L_ + mt * 128;       // Plt rows
  int brow0 = B_ * L_ + b * L_;        // Prt rows (Pb offset 32768)

  // staging: A 512 chunks (1/thr), B 2048 chunks (4/thr); swizzle slot s of
  // row r holds global chunk s ^ ((r>>1)&3)  [R9 PMC-verified 0-conflict]
  int ra = t >> 2, ca = t & 3;
  const unsigned short* gA = Pb + (size_t)(arow0 + ra) * H_ + ((ca ^ ((ra >> 1) & 3)) << 3);
  const unsigned short* gBu0; const unsigned short* gBu1;
  const unsigned short* gBu2; const unsigned short* gBu3;
  int bd0, bd1, bd2, bd3;
  {
    int ci, r, c;
    ci = t;           r = ci >> 2; c = ci & 3;
    gBu0 = Pb + (size_t)(brow0 + r) * H_ + ((c ^ ((r >> 1) & 3)) << 3); bd0 = ci * 8;
    ci = 512 + t;     r = ci >> 2; c = ci & 3;
    gBu1 = Pb + (size_t)(brow0 + r) * H_ + ((c ^ ((r >> 1) & 3)) << 3); bd1 = ci * 8;
    ci = 1024 + t;    r = ci >> 2; c = ci & 3;
    gBu2 = Pb + (size_t)(brow0 + r) * H_ + ((c ^ ((r >> 1) & 3)) << 3); bd2 = ci * 8;
    ci = 1536 + t;    r = ci >> 2; c = ci & 3;
    gBu3 = Pb + (size_t)(brow0 + r) * H_ + ((c ^ ((r >> 1) & 3)) << 3); bd3 = ci * 8;
  }
  int rd = (l4 ^ ((l15 >> 1) & 3)) * 8;  // fragment-read swizzled chunk

#define SSTG_B01(buf, kt_) { int ko = (kt_) * 32;                  \
    gld16(gBu0 + ko, &Bs2[buf][bd0]); gld16(gBu1 + ko, &Bs2[buf][bd1]); }
#define SSTG_B23A(buf, kt_) { int ko = (kt_) * 32;                 \
    gld16(gBu2 + ko, &Bs2[buf][bd2]); gld16(gBu3 + ko, &Bs2[buf][bd3]); \
    gld16(gA + ko, &As2[buf][t * 8]); }

  f32x4 acc[4][8] = {};

  // prologue: tiles 0 and 1
  SSTG_B01(0, 0); SSTG_B23A(0, 0);
  SSTG_B01(1, 1); SSTG_B23A(1, 1);
  asm volatile("s_waitcnt vmcnt(5)" ::: "memory");  // tile 0 landed
  asm volatile("s_barrier" ::: "memory");

#pragma unroll 1
  for (int j = 0; j < 32; ++j) {
    int buf = j - (j / 3) * 3;            // j % 3
    int nb = buf + 2; if (nb >= 3) nb -= 3;  // (j+2) % 3
    bool st = (j <= 29);
    const unsigned short* Ac = As2[buf];
    const unsigned short* Bc = Bs2[buf];

    bf16x8 aq[4], bq[4];
#pragma unroll
    for (int mi = 0; mi < 4; ++mi)
      aq[mi] = *(const bf16x8*)&Ac[(wr * 64 + mi * 16 + l15) * 32 + rd];
#pragma unroll
    for (int ni = 0; ni < 4; ++ni)
      bq[ni] = *(const bf16x8*)&Bc[(wc * 128 + ni * 16 + l15) * 32 + rd];
    if (st) SSTG_B01(nb, j + 2);
    asm volatile("s_barrier" ::: "memory");
    __builtin_amdgcn_s_setprio(1);
#pragma unroll
    for (int mi = 0; mi < 4; ++mi)
#pragma unroll
      for (int ni = 0; ni < 4; ++ni)
        acc[mi][ni] = __builtin_amdgcn_mfma_f32_16x16x32_bf16(aq[mi], bq[ni], acc[mi][ni], 0, 0, 0);
    __builtin_amdgcn_s_setprio(0);
    asm volatile("s_barrier" ::: "memory");

#pragma unroll
    for (int ni = 0; ni < 4; ++ni)
      bq[ni] = *(const bf16x8*)&Bc[(wc * 128 + 64 + ni * 16 + l15) * 32 + rd];
    if (st) SSTG_B23A(nb, j + 2);
    asm volatile("s_barrier" ::: "memory");
    __builtin_amdgcn_s_setprio(1);
#pragma unroll
    for (int mi = 0; mi < 4; ++mi)
#pragma unroll
      for (int ni = 0; ni < 4; ++ni)
        acc[mi][ni + 4] = __builtin_amdgcn_mfma_f32_16x16x32_bf16(aq[mi], bq[ni], acc[mi][ni + 4], 0, 0, 0);
    __builtin_amdgcn_s_setprio(0);
    if (j < 30)
      asm volatile("s_waitcnt vmcnt(5)" ::: "memory");   // tile j+1 confirmed
    else
      asm volatile("s_waitcnt vmcnt(0)" ::: "memory");
    asm volatile("s_barrier" ::: "memory");
  }
#undef SSTG_B01
#undef SSTG_B23A

  // ---- fused softmax epilogue ----
  float* red = (float*)&As2[0][0];         // [128][4] max
  float* red2 = red + 512;                 // [128][4] sum

  // masks
  float ml[4][4];
#pragma unroll
  for (int mi = 0; mi < 4; ++mi)
#pragma unroll
    for (int rr = 0; rr < 4; ++rr)
      ml[mi][rr] = mask_lt[b * L_ + mt * 128 + wr * 64 + mi * 16 + l4 * 4 + rr];
  float mr[8];
#pragma unroll
  for (int ni = 0; ni < 8; ++ni)
    mr[ni] = mask_rt[b * L_ + wc * 128 + ni * 16 + l15];

  // apply pre-softmax mask
#pragma unroll
  for (int mi = 0; mi < 4; ++mi)
#pragma unroll
    for (int ni = 0; ni < 8; ++ni)
#pragma unroll
      for (int rr = 0; rr < 4; ++rr)
        acc[mi][ni][rr] *= ml[mi][rr] * mr[ni];

  // row max: lane-partial over ni, shfl over l15 group, LDS over wc
#pragma unroll
  for (int mi = 0; mi < 4; ++mi)
#pragma unroll
    for (int rr = 0; rr < 4; ++rr) {
      float m = acc[mi][0][rr];
#pragma unroll
      for (int ni = 1; ni < 8; ++ni) m = fmaxf(m, acc[mi][ni][rr]);
      m = fmaxf(m, __shfl_xor(m, 1));
      m = fmaxf(m, __shfl_xor(m, 2));
      m = fmaxf(m, __shfl_xor(m, 4));
      m = fmaxf(m, __shfl_xor(m, 8));
      if (l15 == 0) red[(wr * 64 + mi * 16 + l4 * 4 + rr) * 4 + wc] = m;
    }
  __syncthreads();
  float mfull[4][4];
#pragma unroll
  for (int mi = 0; mi < 4; ++mi)
#pragma unroll
    for (int rr = 0; rr < 4; ++rr) {
      float4 v = *(const float4*)&red[(wr * 64 + mi * 16 + l4 * 4 + rr) * 4];
      mfull[mi][rr] = fmaxf(fmaxf(v.x, v.y), fmaxf(v.z, v.w));
    }

  // exp + row sum
#pragma unroll
  for (int mi = 0; mi < 4; ++mi)
#pragma unroll
    for (int rr = 0; rr < 4; ++rr) {
      float s = 0.f;
#pragma unroll
      for (int ni = 0; ni < 8; ++ni) {
        float e = __expf(acc[mi][ni][rr] - mfull[mi][rr]);
        acc[mi][ni][rr] = e;
        s += e;
      }
      s += __shfl_xor(s, 1);
      s += __shfl_xor(s, 2);
      s += __shfl_xor(s, 4);
      s += __shfl_xor(s, 8);
      if (l15 == 0) red2[(wr * 64 + mi * 16 + l4 * 4 + rr) * 4 + wc] = s;
    }
  __syncthreads();

  float* obase = out + (size_t)b * L_ * L_ + (size_t)(mt * 128) * L_;
#pragma unroll
  for (int mi = 0; mi < 4; ++mi)
#pragma unroll
    for (int rr = 0; rr < 4; ++rr) {
      int row = wr * 64 + mi * 16 + l4 * 4 + rr;
      float4 v = *(const float4*)&red2[row * 4];
      float inv = 1.0f / (((v.x + v.y) + (v.z + v.w)));
      float scale = inv * ml[mi][rr];
#pragma unroll
      for (int ni = 0; ni < 8; ++ni) {
        int col = wc * 128 + ni * 16 + l15;
        obase[(size_t)row * L_ + col] = acc[mi][ni][rr] * scale * mr[ni];
      }
    }
}

extern "C" void kernel_launch(void* const* d_in, const int* in_sizes, int n_in,
                              void* d_out, int out_size, void* d_ws, size_t ws_size,
                              hipStream_t stream) {
  const float* reps_lt = (const float*)d_in[0];
  const float* reps_rt = (const float*)d_in[1];
  const float* mask_lt = (const float*)d_in[2];
  const float* mask_rt = (const float*)d_in[3];
  const float* attn_w1 = (const float*)d_in[4];
  const float* diag    = (const float*)d_in[5];
  float* out = (float*)d_out;

  unsigned short* wt = (unsigned short*)d_ws;           // 2 MB
  unsigned short* pb = wt + (size_t)H_ * A_;            // 128 MB
  unsigned short* xb = pb + (size_t)B_ * L_ * A_ * 2;   // 128 MB

  hipLaunchKernelGGL(wtrans_kernel, dim3(1024), dim3(256), 0, stream, attn_w1, wt);
  hipLaunchKernelGGL(cvt_kernel, dim3(8192), dim3(256), 0, stream,
                     reps_lt, reps_rt, xb);
  hipLaunchKernelGGL(proj8_kernel, dim3(1024), dim3(512), 0, stream,
                     xb, wt, diag, pb);
  hipLaunchKernelGGL(ssmax_kernel, dim3(256), dim3(512), 0, stream,
                     pb, mask_lt, mask_rt, out);
}